// Round 3
// baseline (824.366 us; speedup 1.0000x reference)
//
#include <hip/hip_runtime.h>
#include <math.h>

// PhaseNN on MI355X.  ROUND 14: attack the per-eval table stream (512 KB/CU/eval
// through the ~60 B/cyc L1<->L2 port ~= 8500 cyc/eval, the gap between observed
// 16000 cyc/eval and the ~5000-cyc MFMA floor).
// R13 (476 us) confirmed the wave-width split theory (627->476, no spill).
// R14 changes, bit-identical numerics:
//  (a) T2 LDS slice: ct-tiles 0..23 (96 KiB) live in LDS (we used only 56.6 of
//      160 KiB).  Waves 0..5 read GEMM2 operands via ds_read_b128 (conflict-free,
//      128 B/cyc) -> global T2 stream 256->160 KB/eval; those tiles' global
//      writes in the prologue are dropped (nobody reads them).
//  (b) T2 register prefetch for waves 6..15: ps=0 fragments (8 x i64x2) loaded
//      INSIDE the GEMM1 MFMA loop (stream hides under ~2500 cyc of GEMM1 MFMA,
//      drains at barrier2 per the structural vmcnt(0)-at-__syncthreads), ps=1
//      fragments issued at GEMM2 top under the ps=0 MFMA chains.  Previously all
//      16 T2 loads were exposed serially inside the GEMM2 phase.
// VGPR budget ~110 of the 128 cap (waves_per_eu 4); WRITE_SIZE is the spill
// tripwire.  Structure otherwise identical to R13: 32 blocks x 1024 thr,
// 8 rows/block, fp8 e4m3 tables/feats/w (x64 prescale), 3 barriers/eval.
// ws: T1 256K global | T2 ct>=24 global (160K used of 256K region).

typedef __attribute__((ext_vector_type(4))) float f32x4;
typedef __attribute__((ext_vector_type(2))) float f32x2;
typedef __attribute__((ext_vector_type(8))) short bf16x8;
typedef __attribute__((ext_vector_type(4))) unsigned short u16x4;
typedef __attribute__((ext_vector_type(2))) long i64x2;

struct TCons { float s[64]; float c[64]; };

__device__ __forceinline__ unsigned short f2bf(float f) {
  unsigned u = __builtin_bit_cast(unsigned, f);
  return (unsigned short)((u + 0x7FFFu + ((u >> 16) & 1u)) >> 16);
}
// pack 8 floats -> 8 fp8 e4m3 bytes (HW cvt: byte i <-> value i, LSB first)
__device__ __forceinline__ long pk8fp8(const float* v) {
  unsigned lo = __builtin_amdgcn_cvt_pk_fp8_f32(v[0], v[1], 0, false);
  lo = __builtin_amdgcn_cvt_pk_fp8_f32(v[2], v[3], lo, true);
  unsigned hi = __builtin_amdgcn_cvt_pk_fp8_f32(v[4], v[5], 0, false);
  hi = __builtin_amdgcn_cvt_pk_fp8_f32(v[6], v[7], hi, true);
  return (long)lo | ((long)hi << 32);
}

#define A1_OFF    0        // feats fp8: 16 rows x 256 units x 8 B = 32768 (unit^row)
#define MBUF_OFF  32768    // m partials: 2 kh x 8 rows x 132 f32 = 8448
#define W_OFF     41216    // w fp8 (x64): 16 rows x 16 units x 8 B = 2048 (unit^row)
#define XST_OFF   43264    // 8 rows x 104 chunks x 16 B bf16 (encoder prologue only)
#define RED_OFF   32768    // epilogue overlay: 16 waves x 64 lanes x 16 B
#define ZP_OFF    56576    // 16 B zero page (bf16 epilogue pad cols)
#define T2L_OFF   56592    // T2 ct 0..23 resident: 96 x 64 x 16 B = 98304
#define LDS_BYTES 154896   // 151.3 KiB of 160 KiB

__global__
__attribute__((amdgpu_flat_work_group_size(1024, 1024), amdgpu_waves_per_eu(4, 4)))
void phasenn_kernel(
    const float* __restrict__ x, const float* __restrict__ W_enc,
    const float* __restrict__ b_enc, const float* __restrict__ xi,
    const float* __restrict__ W_out, const float* __restrict__ b_out,
    float* __restrict__ dout, char* __restrict__ wsb, TCons tc)
{
  __shared__ __align__(16) char smem[LDS_BYTES];

  const int tid  = threadIdx.x;
  const int bk   = blockIdx.x;        // rows bk*8 .. bk*8+7
  const int w    = tid >> 6;          // 16 waves
  const int lane = tid & 63;
  const int q    = lane >> 4;
  const int b16  = lane & 15;         // MFMA col slot (batch row duplicated hi/lo)
  const int hi   = b16 >> 3;          // lane owns j = jloc + 2*hi
  const int row8 = b16 & 7;           // batch row within block
  const bool act = (b16 < 8);

  char* T1g = wsb;                    // 256 KiB: (pt 8, ktc 32) x 64 lanes x [cos8|sin8]
  char* T2g = wsb + (256 << 10);      // ct>=24 only: (ct 64, pt2 4) x 64 lanes x [c|s]

  // ---- LDS init (before first barrier): zero pads so hot loops are branchless
  *(f32x4*)(smem + A1_OFF + 16384 + tid*16) = (f32x4){0,0,0,0};  // A1 rows 8..15
  if (tid < 256) *(unsigned*)(smem + W_OFF + 1024 + tid*4) = 0;  // W rows 8..15
  if (tid < 4)   *(unsigned*)(smem + ZP_OFF + tid*4) = 0;

  // ---- xstage: x rows -> bf16 B-frag chunks (chunk ^ row), d>=784 zero (encoder)
  {
    const int row = tid >> 7, dg = tid & 127;
    if (dg < 100) {
      bf16x8 fr = {0,0,0,0,0,0,0,0};
      if (dg < 98) {
        f32x4 v0 = *(const f32x4*)(x + (bk*8 + row)*784 + dg*8);
        f32x4 v1 = *(const f32x4*)(x + (bk*8 + row)*784 + dg*8 + 4);
        #pragma unroll
        for (int i = 0; i < 8; ++i) fr[i] = (short)f2bf(i < 4 ? v0[i] : v1[i-4]);
      }
      *(bf16x8*)(smem + XST_OFF + row*1664 + (((dg ^ row) & 127) << 4)) = fr;
    }
  }

  // ---- table gen: fp8 paired frags.  T1 -> global (identical bytes per block);
  // T2 ct<24 -> LDS (private), ct>=24 -> global.
  if (w < 8) {  // T1: wave = ptile. lane holds p=w*16+b16, n = f*32+q*8+i; [cos|sin]
    const int p = w*16 + b16;
    for (int f = 0; f < 32; ++f) {
      const int n0 = f*32 + q*8;
      f32x4 v0 = *(const f32x4*)(xi + p*1024 + n0);
      f32x4 v1 = *(const f32x4*)(xi + p*1024 + n0 + 4);
      float cv[8], sv[8];
      #pragma unroll
      for (int i = 0; i < 8; ++i) {
        float xv = (i < 4) ? v0[i] : v1[i-4];
        sv[i] = __sinf(xv); cv[i] = __cosf(xv);
      }
      i64x2 pr; pr[0] = pk8fp8(cv); pr[1] = pk8fp8(sv);
      *(i64x2*)(T1g + (size_t)((w*32 + f)*64 + lane)*16) = pr;
    }
  } else {      // T2: lane holds n = ct*16+b16, p = pt2*32+q*8+i; [cos|sin]
    const int w2 = w - 8;
    const bool toLds = (w2 < 3);       // ct 0..23 (wave-uniform)
    for (int f = 0; f < 32; ++f) {
      const int ct = w2*8 + (f >> 2), pt2 = f & 3;
      const int n = ct*16 + b16;
      float cv[8], sv[8];
      #pragma unroll
      for (int i = 0; i < 8; ++i) {
        float xv = xi[(pt2*32 + q*8 + i)*1024 + n];
        sv[i] = __sinf(xv); cv[i] = __cosf(xv);
      }
      i64x2 pr; pr[0] = pk8fp8(cv); pr[1] = pk8fp8(sv);
      if (toLds)
        *(i64x2*)(smem + T2L_OFF + (size_t)((ct*4 + pt2)*64 + lane)*16) = pr;
      else
        *(i64x2*)(T2g + (size_t)((ct*4 + pt2)*64 + lane)*16) = pr;
    }
  }
  __syncthreads();

  // ---- encoder (bf16 MFMA): B cols 8..15 duplicate rows 0..7 so hi lanes get
  // their j=2,3 outputs directly.  Lane owns 8 phases: n=(w*4+jloc+2*hi)*16+q*4+r.
  float p0[8], ka[8], pwv[8];
  {
    f32x4 pac[4] = {{0,0,0,0},{0,0,0,0},{0,0,0,0},{0,0,0,0}};
    for (int kt = 0; kt < 25; ++kt) {
      const char* baddr =
          smem + XST_OFF + row8*1664 + ((((kt*4 + q) ^ row8) & 127) << 4);
      bf16x8 bfr = *(const bf16x8*)baddr;
      const int d = kt*32 + q*8;
      #pragma unroll
      for (int j = 0; j < 4; ++j) {
        bf16x8 afr = {0,0,0,0,0,0,0,0};
        if (d < 784) {
          const int n = (w*4 + j)*16 + b16;
          f32x4 v0 = *(const f32x4*)(W_enc + n*784 + d);
          f32x4 v1 = *(const f32x4*)(W_enc + n*784 + d + 4);
          #pragma unroll
          for (int i = 0; i < 8; ++i) afr[i] = (short)f2bf(i < 4 ? v0[i] : v1[i-4]);
        }
        pac[j] = __builtin_amdgcn_mfma_f32_16x16x32_bf16(afr, bfr, pac[j], 0, 0, 0);
      }
    }
    f32x4 pcA = hi ? pac[2] : pac[0];   // static-index select (rule #20 safe)
    f32x4 pcB = hi ? pac[3] : pac[1];
    #pragma unroll
    for (int r = 0; r < 4; ++r) {
      const int n0 = (w*4 + 2*hi)*16 + q*4 + r;
      float ph0 = 6.283185307179586f / (1.0f + __expf(-(pcA[r] + b_enc[n0])));
      p0[r] = ph0; pwv[r] = ph0; ka[r] = 0.0f;
      const int n1 = (w*4 + 1 + 2*hi)*16 + q*4 + r;
      float ph1 = 6.283185307179586f / (1.0f + __expf(-(pcB[r] + b_enc[n1])));
      p0[4+r] = ph1; pwv[4+r] = ph1; ka[4+r] = 0.0f;
    }
  }

  const float dtf = 0.03125f, half = 0.015625f;
  const float sixth = (float)(0.03125/6.0);

  // hoisted per-wave pointers for the eval loop
  const int pt = w & 7, kh = w >> 3;
  const char* t1b    = T1g + (size_t)((pt*32 + kh*16)*64 + lane)*16;
  const char* a1b    = smem + A1_OFF + b16*2048;
  const char* t2base = T2g + (size_t)(w*16*64 + lane)*16;            // w>=6 only
  const char* t2Lb   = smem + T2L_OFF + (size_t)((w < 6 ? w : 0)*16*64 + lane)*16;

  for (int e = 0; e < 64; ++e) {
    float csv[8], snv[8];
    // ---- Phase A: all 64 lanes, 8 phases each; cache sin/cos for RK4 reuse
    #pragma unroll
    for (int jloc = 0; jloc < 2; ++jloc) {
      #pragma unroll
      for (int r = 0; r < 4; ++r) {
        const int ix = jloc*4 + r;
        snv[ix] = __sinf(pwv[ix]);
        csv[ix] = __cosf(pwv[ix]);
      }
      unsigned cp = __builtin_amdgcn_cvt_pk_fp8_f32(csv[jloc*4+0], csv[jloc*4+1], 0, false);
      cp = __builtin_amdgcn_cvt_pk_fp8_f32(csv[jloc*4+2], csv[jloc*4+3], cp, true);
      unsigned sp = __builtin_amdgcn_cvt_pk_fp8_f32(snv[jloc*4+0], snv[jloc*4+1], 0, false);
      sp = __builtin_amdgcn_cvt_pk_fp8_f32(snv[jloc*4+2], snv[jloc*4+3], sp, true);
      const int u = (w*4 + jloc + 2*hi)*2 + (q >> 1);
      char* base = smem + A1_OFF + row8*2048 + ((q & 1) << 2);
      *(unsigned*)(base + ((u ^ row8) << 3))        = cp;   // cos: units 0..127
      *(unsigned*)(base + 1024 + ((u ^ row8) << 3)) = sp;   // sin: units 128..255
    }
    __syncthreads();

    // ---- GEMM1 fp8 + interleaved T2 ps=0 prefetch (waves 6..15).  The t2r
    // stream hides under GEMM1's MFMAs and drains at barrier2 (structural
    // vmcnt(0) at __syncthreads) instead of being exposed inside GEMM2.
    i64x2 t2r[8];
    {
      f32x4 accC = {0.f, 0.f, 0.f, 0.f}, accS = {0.f, 0.f, 0.f, 0.f};
      #pragma unroll
      for (int i2 = 0; i2 < 16; ++i2) {
        const int ktc = kh*16 + i2;
        i64x2 af = *(const i64x2*)(t1b + (size_t)i2*1024);
        if (w >= 6 && i2 < 8)
          t2r[i2] = *(const i64x2*)(t2base + (size_t)i2*1024);
        long bc = *(const long*)(a1b + (((ktc*4 + q) ^ b16) << 3));
        long bs = *(const long*)(a1b + 1024 + (((ktc*4 + q) ^ b16) << 3));
        accC = __builtin_amdgcn_mfma_f32_16x16x32_fp8_fp8(af[0], bc, accC, 0, 0, 0);
        accS = __builtin_amdgcn_mfma_f32_16x16x32_fp8_fp8(af[1], bs, accS, 0, 0, 0);
      }
      if (act) {
        f32x4 acc = accC + accS;
        *(f32x4*)(smem + MBUF_OFF + kh*4224 + b16*528 + ((pt*16 + q*4) << 2)) = acc;
      }
    }
    __syncthreads();

    // ---- softmax (waves 0..7, wave = row): w fp8 prescaled x64; DUP store to
    // rows 8..15 so GEMM2's pad cols compute each row's sums for the hi lanes.
    if (w < 8) {
      const char* mb = smem + MBUF_OFF + w*528 + lane*8;
      f32x2 u0 = *(const f32x2*)(mb);
      f32x2 u1 = *(const f32x2*)(mb + 4224);
      float e0 = __expf((u0[0] + u1[0]) * 0.001953125f);  // BETA/N = 2/1024
      float e1 = __expf((u0[1] + u1[1]) * 0.001953125f);
      float s = e0 + e1;
      #pragma unroll
      for (int off = 1; off < 64; off <<= 1) s += __shfl_xor(s, off, 64);
      const float inv64 = 64.0f / s;
      unsigned pk = __builtin_amdgcn_cvt_pk_fp8_f32(e0*inv64, e1*inv64, 0, false);
      const int pp = lane*2, u = pp >> 3;
      *(unsigned short*)(smem + W_OFF + w*128 + ((u ^ w) << 3) + (pp & 7)) =
          (unsigned short)pk;
      *(unsigned short*)(smem + W_OFF + (w+8)*128 + ((u ^ (w+8)) << 3) + (pp & 7)) =
          (unsigned short)pk;
    }
    __syncthreads();

    // ---- GEMM2 fp8 + RK4: waves 0..5 read T2 from LDS; waves 6..15 use the
    // prefetched ps=0 regs, ps=1 inline (issues under the ps=0 MFMA chains).
    {
      const float swt = tc.s[e], cwt = tc.c[e];
      const int st = e & 3;
      long wfr[4];
      #pragma unroll
      for (int pt2 = 0; pt2 < 4; ++pt2)
        wfr[pt2] = *(const long*)(smem + W_OFF + b16*128 + (((pt2*4 + q) ^ b16) << 3));
      f32x4 aCk[2][2] = {{{0,0,0,0},{0,0,0,0}},{{0,0,0,0},{0,0,0,0}}};
      f32x4 aSk[2][2] = {{{0,0,0,0},{0,0,0,0}},{{0,0,0,0},{0,0,0,0}}};
      if (w < 6) {
        #pragma unroll
        for (int ps = 0; ps < 2; ++ps)
          #pragma unroll
          for (int jj = 0; jj < 2; ++jj)
            #pragma unroll
            for (int pt2 = 0; pt2 < 4; ++pt2) {
              i64x2 tf = *(const i64x2*)(t2Lb + (size_t)(ps*8 + jj*4 + pt2)*1024);
              aCk[ps][jj] = __builtin_amdgcn_mfma_f32_16x16x32_fp8_fp8(tf[0], wfr[pt2], aCk[ps][jj], 0,0,0);
              aSk[ps][jj] = __builtin_amdgcn_mfma_f32_16x16x32_fp8_fp8(tf[1], wfr[pt2], aSk[ps][jj], 0,0,0);
            }
      } else {
        #pragma unroll
        for (int jj = 0; jj < 2; ++jj)
          #pragma unroll
          for (int pt2 = 0; pt2 < 4; ++pt2) {
            i64x2 tf = t2r[jj*4 + pt2];
            aCk[0][jj] = __builtin_amdgcn_mfma_f32_16x16x32_fp8_fp8(tf[0], wfr[pt2], aCk[0][jj], 0,0,0);
            aSk[0][jj] = __builtin_amdgcn_mfma_f32_16x16x32_fp8_fp8(tf[1], wfr[pt2], aSk[0][jj], 0,0,0);
          }
        #pragma unroll
        for (int jj = 0; jj < 2; ++jj)
          #pragma unroll
          for (int pt2 = 0; pt2 < 4; ++pt2) {
            i64x2 tf = *(const i64x2*)(t2base + (size_t)(8 + jj*4 + pt2)*1024);
            aCk[1][jj] = __builtin_amdgcn_mfma_f32_16x16x32_fp8_fp8(tf[0], wfr[pt2], aCk[1][jj], 0,0,0);
            aSk[1][jj] = __builtin_amdgcn_mfma_f32_16x16x32_fp8_fp8(tf[1], wfr[pt2], aSk[1][jj], 0,0,0);
          }
      }
      #pragma unroll
      for (int jloc = 0; jloc < 2; ++jloc) {
        #pragma unroll
        for (int r = 0; r < 4; ++r) {
          const int ix = jloc*4 + r;
          float vC = hi ? aCk[1][jloc][r] : aCk[0][jloc][r];
          float vS = hi ? aSk[1][jloc][r] : aSk[0][jloc][r];
          float s_ = snv[ix];
          float c_ = csv[ix];
          float kv = (s_*vC - c_*vS) * 0.015625f   // /64 rescale
                   + 0.08f*(swt*c_ - cwt*s_);      // A*sin(wt - phi)
          if (st == 0)      { ka[ix]  = kv;           pwv[ix] = p0[ix] + kv*half; }
          else if (st == 1) { ka[ix] += 2.0f*kv;      pwv[ix] = p0[ix] + kv*half; }
          else if (st == 2) { ka[ix] += 2.0f*kv;      pwv[ix] = p0[ix] + kv*dtf;  }
          else { ka[ix] += kv; p0[ix] += ka[ix]*sixth; pwv[ix] = p0[ix]; }
        }
      }
    }
  }

  // ---- epilogue (bf16 MFMA): out = [cos phiT, sin phiT] @ W_out^T + b_out
  __syncthreads();
  {  // pack feats bf16 into A1 region (rows 0..7, 4-KB stride); all lanes, 8 each
    #pragma unroll
    for (int jloc = 0; jloc < 2; ++jloc) {
      u16x4 cp, sp;
      #pragma unroll
      for (int r = 0; r < 4; ++r) {
        float ph = p0[jloc*4 + r];
        cp[r] = f2bf(__cosf(ph)); sp[r] = f2bf(__sinf(ph));
      }
      const int cj = (w*4 + jloc + 2*hi)*2 + (q >> 1);
      char* base = smem + A1_OFF + row8*4096 + ((q & 1) << 3);
      *(u16x4*)(base + ((cj ^ row8) << 4))        = cp;
      *(u16x4*)(base + ((cj ^ row8) << 4) + 2048) = sp;
    }
  }
  __syncthreads();
  {  // D[cl][row] partial over this wave's 4 ktiles; A = W_out rows (cl<10, pad 0)
    f32x4 acc = {0.f, 0.f, 0.f, 0.f};
    #pragma unroll
    for (int i2 = 0; i2 < 4; ++i2) {
      const int kt = w*4 + i2;
      const int k = kt*32 + q*8;
      bf16x8 afr = {0,0,0,0,0,0,0,0};
      if (b16 < 10) {
        f32x4 v0 = *(const f32x4*)(W_out + b16*2048 + k);
        f32x4 v1 = *(const f32x4*)(W_out + b16*2048 + k + 4);
        #pragma unroll
        for (int i = 0; i < 8; ++i) afr[i] = (short)f2bf(i < 4 ? v0[i] : v1[i-4]);
      }
      const char* baddr = act
          ? (smem + A1_OFF + b16*4096 + ((((kt*4 + q) ^ b16) & 255) << 4))
          : (smem + ZP_OFF);
      bf16x8 bfr = *(const bf16x8*)baddr;
      acc = __builtin_amdgcn_mfma_f32_16x16x32_bf16(afr, bfr, acc, 0, 0, 0);
    }
    *(f32x4*)(smem + RED_OFF + ((w*64 + lane) << 4)) = acc;
  }
  __syncthreads();
  if (tid < 64) {   // reduce 16 wave-partials; lane: row = tid&15, cl = (tid>>4)*4+r
    f32x4 s = {0.f, 0.f, 0.f, 0.f};
    #pragma unroll
    for (int w2 = 0; w2 < 16; ++w2)
      s += *(const f32x4*)(smem + RED_OFF + ((w2*64 + tid) << 4));
    const int b = tid & 15, q2 = tid >> 4;
    if (b < 8) {
      #pragma unroll
      for (int r = 0; r < 4; ++r) {
        const int cl = q2*4 + r;
        if (cl < 10)
          dout[(bk*8 + b)*10 + cl] = s[r] + b_out[cl];
      }
    }
  }
}

extern "C" void kernel_launch(void* const* d_in, const int* in_sizes, int n_in,
                              void* d_out, int out_size, void* d_ws, size_t ws_size,
                              hipStream_t stream) {
  (void)in_sizes; (void)n_in; (void)ws_size; (void)out_size;
  const float* x     = (const float*)d_in[0];
  const float* W_enc = (const float*)d_in[1];
  const float* b_enc = (const float*)d_in[2];
  const float* xi    = (const float*)d_in[3];
  const float* W_out = (const float*)d_in[4];
  const float* b_out = (const float*)d_in[5];
  float* out = (float*)d_out;
  char* wsb = (char*)d_ws;   // 512 KiB fp8 tables; T1 + T2(ct>=24) rewritten per launch

  TCons tc;
  const double OME = 2.0 * 3.14159265358979323846 * 200.0;
  const double dtd = 0.03125;
  const double co[4] = {0.0, 0.5, 0.5, 1.0};
  for (int e = 0; e < 64; ++e) {
    double t = ((double)(e >> 2) + co[e & 3]) * dtd;
    tc.s[e] = (float)sin(OME * t);
    tc.c[e] = (float)cos(OME * t);
  }

  phasenn_kernel<<<dim3(32), dim3(1024), 0, stream>>>(
      x, W_enc, b_enc, xi, W_out, b_out, out, wsb, tc);
}

// Round 4
// 491.761 us; speedup vs baseline: 1.6764x; 1.6764x over previous
//
#include <hip/hip_runtime.h>
#include <math.h>

// PhaseNN on MI355X.  ROUND 15: R13 structure + T2-LDS slice ONLY.
// R14 post-mortem: 476->775 us regression was VGPR spill (WRITE_SIZE 5.0->13.3 MB
// at pinned VGPR=64), caused by the t2r[8] prefetch array (16 VGPR live across
// the softmax barrier) + hoisted pointers -- NOT by the T2-LDS slice (bank
// conflicts unchanged, absmax identical).  R15 keeps the slice, drops all
// register-pressure additions; pointers recomputed per phase exactly as R13.
//  - T2 ct 0..23 (96 KiB) resident in LDS; waves 0..5 read GEMM2 operands via
//    ds_read_b128 (128 B/cyc, conflict-free); waves 6..15 stream global as R13.
//    Per-CU table stream 512 -> 416 KB/eval.
//  - ct<24 global prologue writes dropped (nobody reads them).
// Tripwire: WRITE_SIZE > 6 MB = spill -> revert.
// Structure otherwise identical to R13: 32 blocks x 1024 thr, 8 rows/block,
// fp8 e4m3 tables/feats/w (x64 prescale), 3 barriers/eval, wave-width state
// split (B-operand duplication, 8 phases/lane), trig cache Phase A -> RK4.
// ws: T1 256K global | T2 ct>=24 global.

typedef __attribute__((ext_vector_type(4))) float f32x4;
typedef __attribute__((ext_vector_type(2))) float f32x2;
typedef __attribute__((ext_vector_type(8))) short bf16x8;
typedef __attribute__((ext_vector_type(4))) unsigned short u16x4;
typedef __attribute__((ext_vector_type(2))) long i64x2;

struct TCons { float s[64]; float c[64]; };

__device__ __forceinline__ unsigned short f2bf(float f) {
  unsigned u = __builtin_bit_cast(unsigned, f);
  return (unsigned short)((u + 0x7FFFu + ((u >> 16) & 1u)) >> 16);
}
// pack 8 floats -> 8 fp8 e4m3 bytes (HW cvt: byte i <-> value i, LSB first)
__device__ __forceinline__ long pk8fp8(const float* v) {
  unsigned lo = __builtin_amdgcn_cvt_pk_fp8_f32(v[0], v[1], 0, false);
  lo = __builtin_amdgcn_cvt_pk_fp8_f32(v[2], v[3], lo, true);
  unsigned hi = __builtin_amdgcn_cvt_pk_fp8_f32(v[4], v[5], 0, false);
  hi = __builtin_amdgcn_cvt_pk_fp8_f32(v[6], v[7], hi, true);
  return (long)lo | ((long)hi << 32);
}

#define A1_OFF    0        // feats fp8: 16 rows x 256 units x 8 B = 32768 (unit^row)
#define MBUF_OFF  32768    // m partials: 2 kh x 8 rows x 132 f32 = 8448
#define W_OFF     41216    // w fp8 (x64): 16 rows x 16 units x 8 B = 2048 (unit^row)
#define XST_OFF   43264    // 8 rows x 104 chunks x 16 B bf16 (encoder prologue only)
#define RED_OFF   32768    // epilogue overlay: 16 waves x 64 lanes x 16 B
#define ZP_OFF    56576    // 16 B zero page (bf16 epilogue pad cols)
#define T2L_OFF   56592    // T2 ct 0..23 resident: 96 x 64 x 16 B = 98304
#define LDS_BYTES 154896   // 151.3 KiB of 160 KiB

__global__
__attribute__((amdgpu_flat_work_group_size(1024, 1024), amdgpu_waves_per_eu(4, 4)))
void phasenn_kernel(
    const float* __restrict__ x, const float* __restrict__ W_enc,
    const float* __restrict__ b_enc, const float* __restrict__ xi,
    const float* __restrict__ W_out, const float* __restrict__ b_out,
    float* __restrict__ dout, char* __restrict__ wsb, TCons tc)
{
  __shared__ __align__(16) char smem[LDS_BYTES];

  const int tid  = threadIdx.x;
  const int bk   = blockIdx.x;        // rows bk*8 .. bk*8+7
  const int w    = tid >> 6;          // 16 waves
  const int lane = tid & 63;
  const int q    = lane >> 4;
  const int b16  = lane & 15;         // MFMA col slot (batch row duplicated hi/lo)
  const int hi   = b16 >> 3;          // lane owns j = jloc + 2*hi
  const int row8 = b16 & 7;           // batch row within block
  const bool act = (b16 < 8);

  char* T1g = wsb;                    // 256 KiB: (pt 8, ktc 32) x 64 lanes x [cos8|sin8]
  char* T2g = wsb + (256 << 10);      // ct>=24 only: (ct 64, pt2 4) x 64 lanes x [c|s]

  // ---- LDS init (before first barrier): zero pads so hot loops are branchless
  *(f32x4*)(smem + A1_OFF + 16384 + tid*16) = (f32x4){0,0,0,0};  // A1 rows 8..15
  if (tid < 256) *(unsigned*)(smem + W_OFF + 1024 + tid*4) = 0;  // W rows 8..15
  if (tid < 4)   *(unsigned*)(smem + ZP_OFF + tid*4) = 0;

  // ---- xstage: x rows -> bf16 B-frag chunks (chunk ^ row), d>=784 zero (encoder)
  {
    const int row = tid >> 7, dg = tid & 127;
    if (dg < 100) {
      bf16x8 fr = {0,0,0,0,0,0,0,0};
      if (dg < 98) {
        f32x4 v0 = *(const f32x4*)(x + (bk*8 + row)*784 + dg*8);
        f32x4 v1 = *(const f32x4*)(x + (bk*8 + row)*784 + dg*8 + 4);
        #pragma unroll
        for (int i = 0; i < 8; ++i) fr[i] = (short)f2bf(i < 4 ? v0[i] : v1[i-4]);
      }
      *(bf16x8*)(smem + XST_OFF + row*1664 + (((dg ^ row) & 127) << 4)) = fr;
    }
  }

  // ---- table gen: fp8 paired frags.  T1 -> global (identical bytes per block);
  // T2 ct<24 -> LDS (private), ct>=24 -> global.
  if (w < 8) {  // T1: wave = ptile. lane holds p=w*16+b16, n = f*32+q*8+i; [cos|sin]
    const int p = w*16 + b16;
    for (int f = 0; f < 32; ++f) {
      const int n0 = f*32 + q*8;
      f32x4 v0 = *(const f32x4*)(xi + p*1024 + n0);
      f32x4 v1 = *(const f32x4*)(xi + p*1024 + n0 + 4);
      float cv[8], sv[8];
      #pragma unroll
      for (int i = 0; i < 8; ++i) {
        float xv = (i < 4) ? v0[i] : v1[i-4];
        sv[i] = __sinf(xv); cv[i] = __cosf(xv);
      }
      i64x2 pr; pr[0] = pk8fp8(cv); pr[1] = pk8fp8(sv);
      *(i64x2*)(T1g + (size_t)((w*32 + f)*64 + lane)*16) = pr;
    }
  } else {      // T2: lane holds n = ct*16+b16, p = pt2*32+q*8+i; [cos|sin]
    const int w2 = w - 8;
    const bool toLds = (w2 < 3);       // ct 0..23 (wave-uniform)
    for (int f = 0; f < 32; ++f) {
      const int ct = w2*8 + (f >> 2), pt2 = f & 3;
      const int n = ct*16 + b16;
      float cv[8], sv[8];
      #pragma unroll
      for (int i = 0; i < 8; ++i) {
        float xv = xi[(pt2*32 + q*8 + i)*1024 + n];
        sv[i] = __sinf(xv); cv[i] = __cosf(xv);
      }
      i64x2 pr; pr[0] = pk8fp8(cv); pr[1] = pk8fp8(sv);
      if (toLds)
        *(i64x2*)(smem + T2L_OFF + (size_t)((ct*4 + pt2)*64 + lane)*16) = pr;
      else
        *(i64x2*)(T2g + (size_t)((ct*4 + pt2)*64 + lane)*16) = pr;
    }
  }
  __syncthreads();

  // ---- encoder (bf16 MFMA): B cols 8..15 duplicate rows 0..7 so hi lanes get
  // their j=2,3 outputs directly.  Lane owns 8 phases: n=(w*4+jloc+2*hi)*16+q*4+r.
  float p0[8], ka[8], pwv[8];
  {
    f32x4 pac[4] = {{0,0,0,0},{0,0,0,0},{0,0,0,0},{0,0,0,0}};
    for (int kt = 0; kt < 25; ++kt) {
      const char* baddr =
          smem + XST_OFF + row8*1664 + ((((kt*4 + q) ^ row8) & 127) << 4);
      bf16x8 bfr = *(const bf16x8*)baddr;
      const int d = kt*32 + q*8;
      #pragma unroll
      for (int j = 0; j < 4; ++j) {
        bf16x8 afr = {0,0,0,0,0,0,0,0};
        if (d < 784) {
          const int n = (w*4 + j)*16 + b16;
          f32x4 v0 = *(const f32x4*)(W_enc + n*784 + d);
          f32x4 v1 = *(const f32x4*)(W_enc + n*784 + d + 4);
          #pragma unroll
          for (int i = 0; i < 8; ++i) afr[i] = (short)f2bf(i < 4 ? v0[i] : v1[i-4]);
        }
        pac[j] = __builtin_amdgcn_mfma_f32_16x16x32_bf16(afr, bfr, pac[j], 0, 0, 0);
      }
    }
    f32x4 pcA = hi ? pac[2] : pac[0];   // static-index select (rule #20 safe)
    f32x4 pcB = hi ? pac[3] : pac[1];
    #pragma unroll
    for (int r = 0; r < 4; ++r) {
      const int n0 = (w*4 + 2*hi)*16 + q*4 + r;
      float ph0 = 6.283185307179586f / (1.0f + __expf(-(pcA[r] + b_enc[n0])));
      p0[r] = ph0; pwv[r] = ph0; ka[r] = 0.0f;
      const int n1 = (w*4 + 1 + 2*hi)*16 + q*4 + r;
      float ph1 = 6.283185307179586f / (1.0f + __expf(-(pcB[r] + b_enc[n1])));
      p0[4+r] = ph1; pwv[4+r] = ph1; ka[4+r] = 0.0f;
    }
  }

  const float dtf = 0.03125f, half = 0.015625f;
  const float sixth = (float)(0.03125/6.0);

  for (int e = 0; e < 64; ++e) {
    float csv[8], snv[8];
    // ---- Phase A: all 64 lanes, 8 phases each; cache sin/cos for RK4 reuse
    #pragma unroll
    for (int jloc = 0; jloc < 2; ++jloc) {
      #pragma unroll
      for (int r = 0; r < 4; ++r) {
        const int ix = jloc*4 + r;
        snv[ix] = __sinf(pwv[ix]);
        csv[ix] = __cosf(pwv[ix]);
      }
      unsigned cp = __builtin_amdgcn_cvt_pk_fp8_f32(csv[jloc*4+0], csv[jloc*4+1], 0, false);
      cp = __builtin_amdgcn_cvt_pk_fp8_f32(csv[jloc*4+2], csv[jloc*4+3], cp, true);
      unsigned sp = __builtin_amdgcn_cvt_pk_fp8_f32(snv[jloc*4+0], snv[jloc*4+1], 0, false);
      sp = __builtin_amdgcn_cvt_pk_fp8_f32(snv[jloc*4+2], snv[jloc*4+3], sp, true);
      const int u = (w*4 + jloc + 2*hi)*2 + (q >> 1);
      char* base = smem + A1_OFF + row8*2048 + ((q & 1) << 2);
      *(unsigned*)(base + ((u ^ row8) << 3))        = cp;   // cos: units 0..127
      *(unsigned*)(base + 1024 + ((u ^ row8) << 3)) = sp;   // sin: units 128..255
    }
    __syncthreads();

    // ---- GEMM1 fp8: m[p][row]; wave = (pt=w&7, kh=w>>3); independent cos/sin accs
    {
      const int pt = w & 7, kh = w >> 3;
      f32x4 accC = {0.f, 0.f, 0.f, 0.f}, accS = {0.f, 0.f, 0.f, 0.f};
      const char* t1b = T1g + (size_t)((pt*32 + kh*16)*64 + lane)*16;
      const char* a1b = smem + A1_OFF + b16*2048;
      #pragma unroll 8
      for (int i2 = 0; i2 < 16; ++i2) {
        const int ktc = kh*16 + i2;
        i64x2 af = *(const i64x2*)(t1b + (size_t)i2*1024);
        long bc = *(const long*)(a1b + (((ktc*4 + q) ^ b16) << 3));
        long bs = *(const long*)(a1b + 1024 + (((ktc*4 + q) ^ b16) << 3));
        accC = __builtin_amdgcn_mfma_f32_16x16x32_fp8_fp8(af[0], bc, accC, 0, 0, 0);
        accS = __builtin_amdgcn_mfma_f32_16x16x32_fp8_fp8(af[1], bs, accS, 0, 0, 0);
      }
      if (act) {
        f32x4 acc = accC + accS;
        *(f32x4*)(smem + MBUF_OFF + kh*4224 + b16*528 + ((pt*16 + q*4) << 2)) = acc;
      }
    }
    __syncthreads();

    // ---- softmax (waves 0..7, wave = row): w fp8 prescaled x64; DUP store to
    // rows 8..15 so GEMM2's pad cols compute each row's sums for the hi lanes.
    if (w < 8) {
      const char* mb = smem + MBUF_OFF + w*528 + lane*8;
      f32x2 u0 = *(const f32x2*)(mb);
      f32x2 u1 = *(const f32x2*)(mb + 4224);
      float e0 = __expf((u0[0] + u1[0]) * 0.001953125f);  // BETA/N = 2/1024
      float e1 = __expf((u0[1] + u1[1]) * 0.001953125f);
      float s = e0 + e1;
      #pragma unroll
      for (int off = 1; off < 64; off <<= 1) s += __shfl_xor(s, off, 64);
      const float inv64 = 64.0f / s;
      unsigned pk = __builtin_amdgcn_cvt_pk_fp8_f32(e0*inv64, e1*inv64, 0, false);
      const int pp = lane*2, u = pp >> 3;
      *(unsigned short*)(smem + W_OFF + w*128 + ((u ^ w) << 3) + (pp & 7)) =
          (unsigned short)pk;
      *(unsigned short*)(smem + W_OFF + (w+8)*128 + ((u ^ (w+8)) << 3) + (pp & 7)) =
          (unsigned short)pk;
    }
    __syncthreads();

    // ---- GEMM2 fp8 + RK4: waves 0..5 read T2 from LDS (ds_read_b128), waves
    // 6..15 stream global exactly as R13.  Same loop shape both paths.
    {
      const float swt = tc.s[e], cwt = tc.c[e];
      const int st = e & 3;
      long wfr[4];
      #pragma unroll
      for (int pt2 = 0; pt2 < 4; ++pt2)
        wfr[pt2] = *(const long*)(smem + W_OFF + b16*128 + (((pt2*4 + q) ^ b16) << 3));
      f32x4 aCk[2][2] = {{{0,0,0,0},{0,0,0,0}},{{0,0,0,0},{0,0,0,0}}};
      f32x4 aSk[2][2] = {{{0,0,0,0},{0,0,0,0}},{{0,0,0,0},{0,0,0,0}}};
      if (w < 6) {
        const char* t2Lb = smem + T2L_OFF + (size_t)(w*16*64 + lane)*16;
        #pragma unroll
        for (int ps = 0; ps < 2; ++ps)
          #pragma unroll
          for (int jj = 0; jj < 2; ++jj)
            #pragma unroll
            for (int pt2 = 0; pt2 < 4; ++pt2) {
              i64x2 tf = *(const i64x2*)(t2Lb + (size_t)(ps*8 + jj*4 + pt2)*1024);
              aCk[ps][jj] = __builtin_amdgcn_mfma_f32_16x16x32_fp8_fp8(tf[0], wfr[pt2], aCk[ps][jj], 0,0,0);
              aSk[ps][jj] = __builtin_amdgcn_mfma_f32_16x16x32_fp8_fp8(tf[1], wfr[pt2], aSk[ps][jj], 0,0,0);
            }
      } else {
        const char* t2b = T2g + (size_t)(w*16*64 + lane)*16;
        #pragma unroll
        for (int ps = 0; ps < 2; ++ps)
          #pragma unroll
          for (int jj = 0; jj < 2; ++jj)
            #pragma unroll
            for (int pt2 = 0; pt2 < 4; ++pt2) {
              i64x2 tf = *(const i64x2*)(t2b + (size_t)(ps*8 + jj*4 + pt2)*1024);
              aCk[ps][jj] = __builtin_amdgcn_mfma_f32_16x16x32_fp8_fp8(tf[0], wfr[pt2], aCk[ps][jj], 0,0,0);
              aSk[ps][jj] = __builtin_amdgcn_mfma_f32_16x16x32_fp8_fp8(tf[1], wfr[pt2], aSk[ps][jj], 0,0,0);
            }
      }
      #pragma unroll
      for (int jloc = 0; jloc < 2; ++jloc) {
        #pragma unroll
        for (int r = 0; r < 4; ++r) {
          const int ix = jloc*4 + r;
          float vC = hi ? aCk[1][jloc][r] : aCk[0][jloc][r];
          float vS = hi ? aSk[1][jloc][r] : aSk[0][jloc][r];
          float s_ = snv[ix];
          float c_ = csv[ix];
          float kv = (s_*vC - c_*vS) * 0.015625f   // /64 rescale
                   + 0.08f*(swt*c_ - cwt*s_);      // A*sin(wt - phi)
          if (st == 0)      { ka[ix]  = kv;           pwv[ix] = p0[ix] + kv*half; }
          else if (st == 1) { ka[ix] += 2.0f*kv;      pwv[ix] = p0[ix] + kv*half; }
          else if (st == 2) { ka[ix] += 2.0f*kv;      pwv[ix] = p0[ix] + kv*dtf;  }
          else { ka[ix] += kv; p0[ix] += ka[ix]*sixth; pwv[ix] = p0[ix]; }
        }
      }
    }
  }

  // ---- epilogue (bf16 MFMA): out = [cos phiT, sin phiT] @ W_out^T + b_out
  __syncthreads();
  {  // pack feats bf16 into A1 region (rows 0..7, 4-KB stride); all lanes, 8 each
    #pragma unroll
    for (int jloc = 0; jloc < 2; ++jloc) {
      u16x4 cp, sp;
      #pragma unroll
      for (int r = 0; r < 4; ++r) {
        float ph = p0[jloc*4 + r];
        cp[r] = f2bf(__cosf(ph)); sp[r] = f2bf(__sinf(ph));
      }
      const int cj = (w*4 + jloc + 2*hi)*2 + (q >> 1);
      char* base = smem + A1_OFF + row8*4096 + ((q & 1) << 3);
      *(u16x4*)(base + ((cj ^ row8) << 4))        = cp;
      *(u16x4*)(base + ((cj ^ row8) << 4) + 2048) = sp;
    }
  }
  __syncthreads();
  {  // D[cl][row] partial over this wave's 4 ktiles; A = W_out rows (cl<10, pad 0)
    f32x4 acc = {0.f, 0.f, 0.f, 0.f};
    #pragma unroll
    for (int i2 = 0; i2 < 4; ++i2) {
      const int kt = w*4 + i2;
      const int k = kt*32 + q*8;
      bf16x8 afr = {0,0,0,0,0,0,0,0};
      if (b16 < 10) {
        f32x4 v0 = *(const f32x4*)(W_out + b16*2048 + k);
        f32x4 v1 = *(const f32x4*)(W_out + b16*2048 + k + 4);
        #pragma unroll
        for (int i = 0; i < 8; ++i) afr[i] = (short)f2bf(i < 4 ? v0[i] : v1[i-4]);
      }
      const char* baddr = act
          ? (smem + A1_OFF + b16*4096 + ((((kt*4 + q) ^ b16) & 255) << 4))
          : (smem + ZP_OFF);
      bf16x8 bfr = *(const bf16x8*)baddr;
      acc = __builtin_amdgcn_mfma_f32_16x16x32_bf16(afr, bfr, acc, 0, 0, 0);
    }
    *(f32x4*)(smem + RED_OFF + ((w*64 + lane) << 4)) = acc;
  }
  __syncthreads();
  if (tid < 64) {   // reduce 16 wave-partials; lane: row = tid&15, cl = (tid>>4)*4+r
    f32x4 s = {0.f, 0.f, 0.f, 0.f};
    #pragma unroll
    for (int w2 = 0; w2 < 16; ++w2)
      s += *(const f32x4*)(smem + RED_OFF + ((w2*64 + tid) << 4));
    const int b = tid & 15, q2 = tid >> 4;
    if (b < 8) {
      #pragma unroll
      for (int r = 0; r < 4; ++r) {
        const int cl = q2*4 + r;
        if (cl < 10)
          dout[(bk*8 + b)*10 + cl] = s[r] + b_out[cl];
      }
    }
  }
}

extern "C" void kernel_launch(void* const* d_in, const int* in_sizes, int n_in,
                              void* d_out, int out_size, void* d_ws, size_t ws_size,
                              hipStream_t stream) {
  (void)in_sizes; (void)n_in; (void)ws_size; (void)out_size;
  const float* x     = (const float*)d_in[0];
  const float* W_enc = (const float*)d_in[1];
  const float* b_enc = (const float*)d_in[2];
  const float* xi    = (const float*)d_in[3];
  const float* W_out = (const float*)d_in[4];
  const float* b_out = (const float*)d_in[5];
  float* out = (float*)d_out;
  char* wsb = (char*)d_ws;   // 512 KiB fp8 tables; T1 + T2(ct>=24) rewritten per launch

  TCons tc;
  const double OME = 2.0 * 3.14159265358979323846 * 200.0;
  const double dtd = 0.03125;
  const double co[4] = {0.0, 0.5, 0.5, 1.0};
  for (int e = 0; e < 64; ++e) {
    double t = ((double)(e >> 2) + co[e & 3]) * dtd;
    tc.s[e] = (float)sin(OME * t);
    tc.c[e] = (float)cos(OME * t);
  }

  phasenn_kernel<<<dim3(32), dim3(1024), 0, stream>>>(
      x, W_enc, b_enc, xi, W_out, b_out, out, wsb, tc);
}

// Round 5
// 432.821 us; speedup vs baseline: 1.9046x; 1.1362x over previous
//
#include <hip/hip_runtime.h>
#include <math.h>

// PhaseNN on MI355X.  ROUND 16: 64 blocks x 4 rows (halve per-lane serial VALU
// again, R12-style) + T2L expanded to ct 0..31 (128 KiB, stream 416->352 KB/eval).
// R15 post-mortem: 448 us; T2-LDS slice worth ~28 us (stream model ~0.3us/KB);
// remaining path ~= stream 6000cy + MFMA 3700cy + PhaseA/RK4 VALU + barriers.
// R16: each lane owns 4 phases (g = b16>>2 selects the n-subtile, row4 = b16&3):
//  - Phase A trig 16->8 trans/lane, RK4 8->4 updates, pack halves, ~20 VGPR freed.
//  - GEMM1/GEMM2 MFMA per wave UNCHANGED (pad cols discarded as before); per-CU
//    stream unchanged; 64 CUs active.  A1 swizzle re-derived: ^(row4*5) spreads
//    the 4 rows across banks; duplicate-lane reads are same-address broadcasts.
//  - A1 8KB (4 rows) + MBUF 4.2KB + XST 6.6KB shrink frees room: T2L ct0..31
//    (128 KiB) -> waves 0..7 read GEMM2 from LDS, waves 8..15 global (ct32..63).
// Numerics operation-identical to R15 -> absmax must stay EXACTLY 0.01171875.
// Tripwire: WRITE_SIZE > 6.5 MB = spill -> revert.
// ws: T1 256K global | T2 ct>=32 global (original offsets).

typedef __attribute__((ext_vector_type(4))) float f32x4;
typedef __attribute__((ext_vector_type(2))) float f32x2;
typedef __attribute__((ext_vector_type(8))) short bf16x8;
typedef __attribute__((ext_vector_type(4))) unsigned short u16x4;
typedef __attribute__((ext_vector_type(2))) long i64x2;

struct TCons { float s[64]; float c[64]; };

__device__ __forceinline__ unsigned short f2bf(float f) {
  unsigned u = __builtin_bit_cast(unsigned, f);
  return (unsigned short)((u + 0x7FFFu + ((u >> 16) & 1u)) >> 16);
}
// pack 8 floats -> 8 fp8 e4m3 bytes (HW cvt: byte i <-> value i, LSB first)
__device__ __forceinline__ long pk8fp8(const float* v) {
  unsigned lo = __builtin_amdgcn_cvt_pk_fp8_f32(v[0], v[1], 0, false);
  lo = __builtin_amdgcn_cvt_pk_fp8_f32(v[2], v[3], lo, true);
  unsigned hi = __builtin_amdgcn_cvt_pk_fp8_f32(v[4], v[5], 0, false);
  hi = __builtin_amdgcn_cvt_pk_fp8_f32(v[6], v[7], hi, true);
  return (long)lo | ((long)hi << 32);
}

#define A1_OFF    0        // GEMM1 feats fp8: 4 rows x 2048 B; epilogue: 4 x 4096 B
#define MBUF_OFF  16384    // m partials: 2 kh x 4 rows x 132 f32 = 4224 (kh stride 2112)
#define W_OFF     20608    // w fp8 (x64): 16 rows x 16 units x 8 B = 2048 (4x dup)
#define ZP_OFF    22656    // 16 B zero page (bf16 epilogue pad cols)
#define XST_OFF   22672    // 4 rows x 104 chunks x 16 B bf16 (encoder prologue only)
#define T2L_OFF   29344    // T2 ct 0..31 resident: 128 x 64 x 16 B = 131072
#define RED_OFF   29344    // epilogue overlay (T2L dead by then): 16 KiB
#define LDS_BYTES 160416   // ~156.7 KiB of 160 KiB

__global__
__attribute__((amdgpu_flat_work_group_size(1024, 1024), amdgpu_waves_per_eu(4, 4)))
void phasenn_kernel(
    const float* __restrict__ x, const float* __restrict__ W_enc,
    const float* __restrict__ b_enc, const float* __restrict__ xi,
    const float* __restrict__ W_out, const float* __restrict__ b_out,
    float* __restrict__ dout, char* __restrict__ wsb, TCons tc)
{
  __shared__ __align__(16) char smem[LDS_BYTES];

  const int tid  = threadIdx.x;
  const int bk   = blockIdx.x;        // rows bk*4 .. bk*4+3
  const int w    = tid >> 6;          // 16 waves
  const int lane = tid & 63;
  const int q    = lane >> 4;
  const int b16  = lane & 15;         // MFMA col slot (batch row duplicated x4)
  const int g    = b16 >> 2;          // lane owns n-subtile j = g (0..3)
  const int row4 = b16 & 3;           // batch row within block
  const int xr5  = row4 * 5;          // A1 bank-spread XOR (toggles low 4 bits)

  char* T1g = wsb;                    // 256 KiB: (pt 8, ktc 32) x 64 lanes x [cos8|sin8]
  char* T2g = wsb + (256 << 10);      // ct>=32 only: (ct,pt2) x 64 lanes x [c|s], orig offsets

  // ---- LDS init: zero page only (A1/W fully rewritten every eval)
  if (tid < 4) *(unsigned*)(smem + ZP_OFF + tid*4) = 0;

  // ---- xstage: x rows -> bf16 B-frag chunks (chunk ^ row), d>=784 zero (encoder)
  {
    const int row = tid >> 7, dg = tid & 127;
    if (row < 4 && dg < 100) {
      bf16x8 fr = {0,0,0,0,0,0,0,0};
      if (dg < 98) {
        f32x4 v0 = *(const f32x4*)(x + (bk*4 + row)*784 + dg*8);
        f32x4 v1 = *(const f32x4*)(x + (bk*4 + row)*784 + dg*8 + 4);
        #pragma unroll
        for (int i = 0; i < 8; ++i) fr[i] = (short)f2bf(i < 4 ? v0[i] : v1[i-4]);
      }
      *(bf16x8*)(smem + XST_OFF + row*1664 + (((dg ^ row) & 127) << 4)) = fr;
    }
  }

  // ---- table gen: fp8 paired frags.  T1 -> global (identical bytes per block);
  // T2 ct<32 -> LDS (private), ct>=32 -> global.
  if (w < 8) {  // T1: wave = ptile. lane holds p=w*16+b16, n = f*32+q*8+i; [cos|sin]
    const int p = w*16 + b16;
    for (int f = 0; f < 32; ++f) {
      const int n0 = f*32 + q*8;
      f32x4 v0 = *(const f32x4*)(xi + p*1024 + n0);
      f32x4 v1 = *(const f32x4*)(xi + p*1024 + n0 + 4);
      float cv[8], sv[8];
      #pragma unroll
      for (int i = 0; i < 8; ++i) {
        float xv = (i < 4) ? v0[i] : v1[i-4];
        sv[i] = __sinf(xv); cv[i] = __cosf(xv);
      }
      i64x2 pr; pr[0] = pk8fp8(cv); pr[1] = pk8fp8(sv);
      *(i64x2*)(T1g + (size_t)((w*32 + f)*64 + lane)*16) = pr;
    }
  } else {      // T2: lane holds n = ct*16+b16, p = pt2*32+q*8+i; [cos|sin]
    const int w2 = w - 8;
    const bool toLds = (w2 < 4);       // ct 0..31 (wave-uniform)
    for (int f = 0; f < 32; ++f) {
      const int ct = w2*8 + (f >> 2), pt2 = f & 3;
      const int n = ct*16 + b16;
      float cv[8], sv[8];
      #pragma unroll
      for (int i = 0; i < 8; ++i) {
        float xv = xi[(pt2*32 + q*8 + i)*1024 + n];
        sv[i] = __sinf(xv); cv[i] = __cosf(xv);
      }
      i64x2 pr; pr[0] = pk8fp8(cv); pr[1] = pk8fp8(sv);
      if (toLds)
        *(i64x2*)(smem + T2L_OFF + (size_t)((ct*4 + pt2)*64 + lane)*16) = pr;
      else
        *(i64x2*)(T2g + (size_t)((ct*4 + pt2)*64 + lane)*16) = pr;
    }
  }
  __syncthreads();

  // ---- encoder (bf16 MFMA): B cols duplicate rows 0..3 (x4); lane keeps
  // pac[g] -> 4 phases: n = (w*4+g)*16 + q*4 + r, batch row row4.
  float p0[4], ka[4], pwv[4];
  {
    f32x4 pac[4] = {{0,0,0,0},{0,0,0,0},{0,0,0,0},{0,0,0,0}};
    for (int kt = 0; kt < 25; ++kt) {
      const char* baddr =
          smem + XST_OFF + row4*1664 + ((((kt*4 + q) ^ row4) & 127) << 4);
      bf16x8 bfr = *(const bf16x8*)baddr;
      const int d = kt*32 + q*8;
      #pragma unroll
      for (int j = 0; j < 4; ++j) {
        bf16x8 afr = {0,0,0,0,0,0,0,0};
        if (d < 784) {
          const int n = (w*4 + j)*16 + b16;
          f32x4 v0 = *(const f32x4*)(W_enc + n*784 + d);
          f32x4 v1 = *(const f32x4*)(W_enc + n*784 + d + 4);
          #pragma unroll
          for (int i = 0; i < 8; ++i) afr[i] = (short)f2bf(i < 4 ? v0[i] : v1[i-4]);
        }
        pac[j] = __builtin_amdgcn_mfma_f32_16x16x32_bf16(afr, bfr, pac[j], 0, 0, 0);
      }
    }
    f32x4 pc = (g==0) ? pac[0] : (g==1) ? pac[1] : (g==2) ? pac[2] : pac[3];
    #pragma unroll
    for (int r = 0; r < 4; ++r) {
      const int n = (w*4 + g)*16 + q*4 + r;
      float ph = 6.283185307179586f / (1.0f + __expf(-(pc[r] + b_enc[n])));
      p0[r] = ph; pwv[r] = ph; ka[r] = 0.0f;
    }
  }

  const float dtf = 0.03125f, half = 0.015625f;
  const float sixth = (float)(0.03125/6.0);

  for (int e = 0; e < 64; ++e) {
    float csv[4], snv[4];
    // ---- Phase A: all 64 lanes, 4 phases each; cache sin/cos for RK4 reuse
    {
      #pragma unroll
      for (int r = 0; r < 4; ++r) {
        snv[r] = __sinf(pwv[r]);
        csv[r] = __cosf(pwv[r]);
      }
      unsigned cp = __builtin_amdgcn_cvt_pk_fp8_f32(csv[0], csv[1], 0, false);
      cp = __builtin_amdgcn_cvt_pk_fp8_f32(csv[2], csv[3], cp, true);
      unsigned sp = __builtin_amdgcn_cvt_pk_fp8_f32(snv[0], snv[1], 0, false);
      sp = __builtin_amdgcn_cvt_pk_fp8_f32(snv[2], snv[3], sp, true);
      const int u = (w*4 + g)*2 + (q >> 1);
      char* base = smem + A1_OFF + row4*2048 + ((q & 1) << 2);
      *(unsigned*)(base + ((u ^ xr5) << 3))        = cp;   // cos: units 0..127
      *(unsigned*)(base + 1024 + ((u ^ xr5) << 3)) = sp;   // sin: units 128..255
    }
    __syncthreads();

    // ---- GEMM1 fp8: m[p][row]; wave = (pt=w&7, kh=w>>3); independent cos/sin accs
    {
      const int pt = w & 7, kh = w >> 3;
      f32x4 accC = {0.f, 0.f, 0.f, 0.f}, accS = {0.f, 0.f, 0.f, 0.f};
      const char* t1b = T1g + (size_t)((pt*32 + kh*16)*64 + lane)*16;
      const char* a1b = smem + A1_OFF + row4*2048;
      #pragma unroll 8
      for (int i2 = 0; i2 < 16; ++i2) {
        const int ktc = kh*16 + i2;
        i64x2 af = *(const i64x2*)(t1b + (size_t)i2*1024);
        long bc = *(const long*)(a1b + (((ktc*4 + q) ^ xr5) << 3));
        long bs = *(const long*)(a1b + 1024 + (((ktc*4 + q) ^ xr5) << 3));
        accC = __builtin_amdgcn_mfma_f32_16x16x32_fp8_fp8(af[0], bc, accC, 0, 0, 0);
        accS = __builtin_amdgcn_mfma_f32_16x16x32_fp8_fp8(af[1], bs, accS, 0, 0, 0);
      }
      if (b16 < 4) {
        f32x4 acc = accC + accS;
        *(f32x4*)(smem + MBUF_OFF + kh*2112 + b16*528 + ((pt*16 + q*4) << 2)) = acc;
      }
    }
    __syncthreads();

    // ---- softmax (waves 0..3, wave = row): w fp8 prescaled x64; store x4 dup
    // to rows w, w+4, w+8, w+12 so GEMM2's cols feed every lane directly.
    if (w < 4) {
      const char* mb = smem + MBUF_OFF + w*528 + lane*8;
      f32x2 u0 = *(const f32x2*)(mb);
      f32x2 u1 = *(const f32x2*)(mb + 2112);
      float e0 = __expf((u0[0] + u1[0]) * 0.001953125f);  // BETA/N = 2/1024
      float e1 = __expf((u0[1] + u1[1]) * 0.001953125f);
      float s = e0 + e1;
      #pragma unroll
      for (int off = 1; off < 64; off <<= 1) s += __shfl_xor(s, off, 64);
      const float inv64 = 64.0f / s;
      unsigned pk = __builtin_amdgcn_cvt_pk_fp8_f32(e0*inv64, e1*inv64, 0, false);
      const int pp = lane*2, u = pp >> 3;
      #pragma unroll
      for (int t = 0; t < 4; ++t) {
        const int rr = w + t*4;
        *(unsigned short*)(smem + W_OFF + rr*128 + ((u ^ rr) << 3) + (pp & 7)) =
            (unsigned short)pk;
      }
    }
    __syncthreads();

    // ---- GEMM2 fp8 + RK4: waves 0..7 read T2 from LDS (ds_read_b128), waves
    // 8..15 stream global.  4 ct accumulators; lane selects c = g; 4-phase RK4
    // with cached trig (no sin/cos here).
    {
      const float swt = tc.s[e], cwt = tc.c[e];
      const int st = e & 3;
      long wfr[4];
      #pragma unroll
      for (int pt2 = 0; pt2 < 4; ++pt2)
        wfr[pt2] = *(const long*)(smem + W_OFF + b16*128 + (((pt2*4 + q) ^ b16) << 3));
      f32x4 aC[4] = {{0,0,0,0},{0,0,0,0},{0,0,0,0},{0,0,0,0}};
      f32x4 aS[4] = {{0,0,0,0},{0,0,0,0},{0,0,0,0},{0,0,0,0}};
      if (w < 8) {
        const char* t2Lb = smem + T2L_OFF + (size_t)(w*16*64 + lane)*16;
        #pragma unroll
        for (int c = 0; c < 4; ++c)
          #pragma unroll
          for (int pt2 = 0; pt2 < 4; ++pt2) {
            i64x2 tf = *(const i64x2*)(t2Lb + (size_t)(c*4 + pt2)*1024);
            aC[c] = __builtin_amdgcn_mfma_f32_16x16x32_fp8_fp8(tf[0], wfr[pt2], aC[c], 0,0,0);
            aS[c] = __builtin_amdgcn_mfma_f32_16x16x32_fp8_fp8(tf[1], wfr[pt2], aS[c], 0,0,0);
          }
      } else {
        const char* t2b = T2g + (size_t)(w*16*64 + lane)*16;
        #pragma unroll
        for (int c = 0; c < 4; ++c)
          #pragma unroll
          for (int pt2 = 0; pt2 < 4; ++pt2) {
            i64x2 tf = *(const i64x2*)(t2b + (size_t)(c*4 + pt2)*1024);
            aC[c] = __builtin_amdgcn_mfma_f32_16x16x32_fp8_fp8(tf[0], wfr[pt2], aC[c], 0,0,0);
            aS[c] = __builtin_amdgcn_mfma_f32_16x16x32_fp8_fp8(tf[1], wfr[pt2], aS[c], 0,0,0);
          }
      }
      f32x4 vC4 = (g==0) ? aC[0] : (g==1) ? aC[1] : (g==2) ? aC[2] : aC[3];
      f32x4 vS4 = (g==0) ? aS[0] : (g==1) ? aS[1] : (g==2) ? aS[2] : aS[3];
      #pragma unroll
      for (int r = 0; r < 4; ++r) {
        float s_ = snv[r];
        float c_ = csv[r];
        float kv = (s_*vC4[r] - c_*vS4[r]) * 0.015625f   // /64 rescale
                 + 0.08f*(swt*c_ - cwt*s_);              // A*sin(wt - phi)
        if (st == 0)      { ka[r]  = kv;           pwv[r] = p0[r] + kv*half; }
        else if (st == 1) { ka[r] += 2.0f*kv;      pwv[r] = p0[r] + kv*half; }
        else if (st == 2) { ka[r] += 2.0f*kv;      pwv[r] = p0[r] + kv*dtf;  }
        else { ka[r] += kv; p0[r] += ka[r]*sixth; pwv[r] = p0[r]; }
      }
    }
  }

  // ---- epilogue (bf16 MFMA): out = [cos phiT, sin phiT] @ W_out^T + b_out
  __syncthreads();
  {  // pack feats bf16 into A1 region (rows 0..3, 4-KB stride); all lanes, 4 each
    u16x4 cp, sp;
    #pragma unroll
    for (int r = 0; r < 4; ++r) {
      float ph = p0[r];
      cp[r] = f2bf(__cosf(ph)); sp[r] = f2bf(__sinf(ph));
    }
    const int cj = (w*4 + g)*2 + (q >> 1);
    char* base = smem + A1_OFF + row4*4096 + ((q & 1) << 3);
    *(u16x4*)(base + ((cj ^ row4) << 4))        = cp;
    *(u16x4*)(base + ((cj ^ row4) << 4) + 2048) = sp;
  }
  __syncthreads();
  {  // D[cl][row] partial over this wave's 4 ktiles; A = W_out rows (cl<10, pad 0)
    f32x4 acc = {0.f, 0.f, 0.f, 0.f};
    #pragma unroll
    for (int i2 = 0; i2 < 4; ++i2) {
      const int kt = w*4 + i2;
      const int k = kt*32 + q*8;
      bf16x8 afr = {0,0,0,0,0,0,0,0};
      if (b16 < 10) {
        f32x4 v0 = *(const f32x4*)(W_out + b16*2048 + k);
        f32x4 v1 = *(const f32x4*)(W_out + b16*2048 + k + 4);
        #pragma unroll
        for (int i = 0; i < 8; ++i) afr[i] = (short)f2bf(i < 4 ? v0[i] : v1[i-4]);
      }
      const char* baddr = (b16 < 4)
          ? (smem + A1_OFF + b16*4096 + ((((kt*4 + q) ^ b16) & 255) << 4))
          : (smem + ZP_OFF);
      bf16x8 bfr = *(const bf16x8*)baddr;
      acc = __builtin_amdgcn_mfma_f32_16x16x32_bf16(afr, bfr, acc, 0, 0, 0);
    }
    *(f32x4*)(smem + RED_OFF + ((w*64 + lane) << 4)) = acc;
  }
  __syncthreads();
  if (tid < 64) {   // reduce 16 wave-partials; lane: row = tid&15, cl = (tid>>4)*4+r
    f32x4 s = {0.f, 0.f, 0.f, 0.f};
    #pragma unroll
    for (int w2 = 0; w2 < 16; ++w2)
      s += *(const f32x4*)(smem + RED_OFF + ((w2*64 + tid) << 4));
    const int b = tid & 15, q2 = tid >> 4;
    if (b < 4) {
      #pragma unroll
      for (int r = 0; r < 4; ++r) {
        const int cl = q2*4 + r;
        if (cl < 10)
          dout[(bk*4 + b)*10 + cl] = s[r] + b_out[cl];
      }
    }
  }
}

extern "C" void kernel_launch(void* const* d_in, const int* in_sizes, int n_in,
                              void* d_out, int out_size, void* d_ws, size_t ws_size,
                              hipStream_t stream) {
  (void)in_sizes; (void)n_in; (void)ws_size; (void)out_size;
  const float* x     = (const float*)d_in[0];
  const float* W_enc = (const float*)d_in[1];
  const float* b_enc = (const float*)d_in[2];
  const float* xi    = (const float*)d_in[3];
  const float* W_out = (const float*)d_in[4];
  const float* b_out = (const float*)d_in[5];
  float* out = (float*)d_out;
  char* wsb = (char*)d_ws;   // 512 KiB fp8 tables; T1 + T2(ct>=32) rewritten per launch

  TCons tc;
  const double OME = 2.0 * 3.14159265358979323846 * 200.0;
  const double dtd = 0.03125;
  const double co[4] = {0.0, 0.5, 0.5, 1.0};
  for (int e = 0; e < 64; ++e) {
    double t = ((double)(e >> 2) + co[e & 3]) * dtd;
    tc.s[e] = (float)sin(OME * t);
    tc.c[e] = (float)cos(OME * t);
  }

  phasenn_kernel<<<dim3(64), dim3(1024), 0, stream>>>(
      x, W_enc, b_enc, xi, W_out, b_out, out, wsb, tc);
}

// Round 6
// 413.555 us; speedup vs baseline: 1.9934x; 1.0466x over previous
//
#include <hip/hip_runtime.h>
#include <math.h>

// PhaseNN on MI355X.  ROUND 17: 128 blocks x 2 rows (third VALU halving) +
// T2L 36 ct tiles (144 KiB, global stream 384->368 KB/eval).
// R16 post-mortem (392 us): per-CU floors stream ~6400cy + MFMA ~5000cy +
// VALU ~5000cy ~= measured 14700cy/eval -> pipes barely overlap (16-wave
// barrier lockstep).  Halving per-lane serial work has paid twice (R12 -24%,
// R16 -12%); do it again:
//  - 8-way column dup (row2 = b16&1, g = b16>>1): lane owns 2 phases
//    (j = b16>>2, rp = (b16>>1)&1, r = rp*2+{0,1}).
//  - Phase A trig 8->4 trans/lane; RK4 2 updates; GEMM2 j-select + rp-select.
//  - softmax: 2 waves, single W store; GEMM2 reads W row (b16&1) directly.
//  - A1/MBUF/XST shrink frees ~14 KB -> T2L ct 0..35 (waves 0..8 read GEMM2
//    operands from LDS; waves 9..15 global ct>=36).
// Numerics operation-identical -> absmax must stay EXACTLY 0.01171875.
// Tripwire: WRITE_SIZE > 5 MB = spill -> revert.
// ws: T1 256K global | T2 ct>=36 global (original offsets).

typedef __attribute__((ext_vector_type(4))) float f32x4;
typedef __attribute__((ext_vector_type(2))) float f32x2;
typedef __attribute__((ext_vector_type(8))) short bf16x8;
typedef __attribute__((ext_vector_type(2))) unsigned short u16x2;
typedef __attribute__((ext_vector_type(2))) long i64x2;

struct TCons { float s[64]; float c[64]; };

__device__ __forceinline__ unsigned short f2bf(float f) {
  unsigned u = __builtin_bit_cast(unsigned, f);
  return (unsigned short)((u + 0x7FFFu + ((u >> 16) & 1u)) >> 16);
}
// pack 8 floats -> 8 fp8 e4m3 bytes (HW cvt: byte i <-> value i, LSB first)
__device__ __forceinline__ long pk8fp8(const float* v) {
  unsigned lo = __builtin_amdgcn_cvt_pk_fp8_f32(v[0], v[1], 0, false);
  lo = __builtin_amdgcn_cvt_pk_fp8_f32(v[2], v[3], lo, true);
  unsigned hi = __builtin_amdgcn_cvt_pk_fp8_f32(v[4], v[5], 0, false);
  hi = __builtin_amdgcn_cvt_pk_fp8_f32(v[6], v[7], hi, true);
  return (long)lo | ((long)hi << 32);
}

#define A1_OFF    0        // GEMM1 feats fp8: 2 rows x 2048 B; epilogue: 2 x 4096 B
#define MBUF_OFF  8192     // m partials: 2 kh x 2 rows x 528 f32B (kh stride 1056)
#define W_OFF     10304    // w fp8 (x64): 2 rows x 16 units x 8 B = 256
#define ZP_OFF    10560    // 16 B zero page (bf16 epilogue pad cols)
#define XST_OFF   10576    // 2 rows x 104 chunks x 16 B bf16 (encoder prologue only)
#define T2L_OFF   13904    // T2 ct 0..35 resident: 144 x 64 x 16 B = 147456
#define RED_OFF   13904    // epilogue overlay (T2L dead by then): 16 KiB
#define LDS_BYTES 161360   // ~157.6 KiB of 160 KiB

__global__
__attribute__((amdgpu_flat_work_group_size(1024, 1024), amdgpu_waves_per_eu(4, 4)))
void phasenn_kernel(
    const float* __restrict__ x, const float* __restrict__ W_enc,
    const float* __restrict__ b_enc, const float* __restrict__ xi,
    const float* __restrict__ W_out, const float* __restrict__ b_out,
    float* __restrict__ dout, char* __restrict__ wsb, TCons tc)
{
  __shared__ __align__(16) char smem[LDS_BYTES];

  const int tid  = threadIdx.x;
  const int bk   = blockIdx.x;        // rows bk*2, bk*2+1
  const int w    = tid >> 6;          // 16 waves
  const int lane = tid & 63;
  const int q    = lane >> 4;
  const int b16  = lane & 15;         // MFMA col slot (batch row duplicated x8)
  const int row2 = b16 & 1;           // batch row within block
  const int j4   = b16 >> 2;          // lane's n-subtile j (0..3)
  const int rp   = (b16 >> 1) & 1;    // lane's r-pair (r = rp*2 + {0,1})
  const int swz  = row2 * 5;          // A1 bank-spread XOR

  char* T1g = wsb;                    // 256 KiB: (pt 8, ktc 32) x 64 lanes x [cos8|sin8]
  char* T2g = wsb + (256 << 10);      // ct>=36 only: (ct,pt2) x 64 lanes x [c|s]

  // ---- LDS init: zero page only (A1/W fully rewritten every eval)
  if (tid < 4) *(unsigned*)(smem + ZP_OFF + tid*4) = 0;

  // ---- xstage: x rows -> bf16 B-frag chunks (chunk ^ row), d>=784 zero (encoder)
  {
    const int row = tid >> 7, dg = tid & 127;
    if (row < 2 && dg < 100) {
      bf16x8 fr = {0,0,0,0,0,0,0,0};
      if (dg < 98) {
        f32x4 v0 = *(const f32x4*)(x + (bk*2 + row)*784 + dg*8);
        f32x4 v1 = *(const f32x4*)(x + (bk*2 + row)*784 + dg*8 + 4);
        #pragma unroll
        for (int i = 0; i < 8; ++i) fr[i] = (short)f2bf(i < 4 ? v0[i] : v1[i-4]);
      }
      *(bf16x8*)(smem + XST_OFF + row*1664 + (((dg ^ row) & 127) << 4)) = fr;
    }
  }

  // ---- table gen: fp8 paired frags.  T1 -> global (identical bytes per block);
  // T2 ct<36 -> LDS (private), ct>=36 -> global.
  if (w < 8) {  // T1: wave = ptile. lane holds p=w*16+b16, n = f*32+q*8+i; [cos|sin]
    const int p = w*16 + b16;
    for (int f = 0; f < 32; ++f) {
      const int n0 = f*32 + q*8;
      f32x4 v0 = *(const f32x4*)(xi + p*1024 + n0);
      f32x4 v1 = *(const f32x4*)(xi + p*1024 + n0 + 4);
      float cv[8], sv[8];
      #pragma unroll
      for (int i = 0; i < 8; ++i) {
        float xv = (i < 4) ? v0[i] : v1[i-4];
        sv[i] = __sinf(xv); cv[i] = __cosf(xv);
      }
      i64x2 pr; pr[0] = pk8fp8(cv); pr[1] = pk8fp8(sv);
      *(i64x2*)(T1g + (size_t)((w*32 + f)*64 + lane)*16) = pr;
    }
  } else {      // T2: lane holds n = ct*16+b16, p = pt2*32+q*8+i; [cos|sin]
    const int w2 = w - 8;
    for (int f = 0; f < 32; ++f) {
      const int ct = w2*8 + (f >> 2), pt2 = f & 3;
      const int n = ct*16 + b16;
      float cv[8], sv[8];
      #pragma unroll
      for (int i = 0; i < 8; ++i) {
        float xv = xi[(pt2*32 + q*8 + i)*1024 + n];
        sv[i] = __sinf(xv); cv[i] = __cosf(xv);
      }
      i64x2 pr; pr[0] = pk8fp8(cv); pr[1] = pk8fp8(sv);
      if (ct < 36)
        *(i64x2*)(smem + T2L_OFF + (size_t)((ct*4 + pt2)*64 + lane)*16) = pr;
      else
        *(i64x2*)(T2g + (size_t)((ct*4 + pt2)*64 + lane)*16) = pr;
    }
  }
  __syncthreads();

  // ---- encoder (bf16 MFMA): B cols duplicate rows 0..1 (x8); lane keeps 2 of
  // pac[j4]: phases n = (w*4+j4)*16 + q*4 + rp*2 + {0,1}, batch row row2.
  float p0[2], ka[2], pwv[2];
  {
    f32x4 pac[4] = {{0,0,0,0},{0,0,0,0},{0,0,0,0},{0,0,0,0}};
    for (int kt = 0; kt < 25; ++kt) {
      const char* baddr =
          smem + XST_OFF + row2*1664 + ((((kt*4 + q) ^ row2) & 127) << 4);
      bf16x8 bfr = *(const bf16x8*)baddr;
      const int d = kt*32 + q*8;
      #pragma unroll
      for (int j = 0; j < 4; ++j) {
        bf16x8 afr = {0,0,0,0,0,0,0,0};
        if (d < 784) {
          const int n = (w*4 + j)*16 + b16;
          f32x4 v0 = *(const f32x4*)(W_enc + n*784 + d);
          f32x4 v1 = *(const f32x4*)(W_enc + n*784 + d + 4);
          #pragma unroll
          for (int i = 0; i < 8; ++i) afr[i] = (short)f2bf(i < 4 ? v0[i] : v1[i-4]);
        }
        pac[j] = __builtin_amdgcn_mfma_f32_16x16x32_bf16(afr, bfr, pac[j], 0, 0, 0);
      }
    }
    f32x4 pc = (j4==0) ? pac[0] : (j4==1) ? pac[1] : (j4==2) ? pac[2] : pac[3];
    float vA = rp ? pc[2] : pc[0];
    float vB = rp ? pc[3] : pc[1];
    const int n0 = (w*4 + j4)*16 + q*4 + rp*2;
    float ph0 = 6.283185307179586f / (1.0f + __expf(-(vA + b_enc[n0])));
    float ph1 = 6.283185307179586f / (1.0f + __expf(-(vB + b_enc[n0 + 1])));
    p0[0] = ph0; pwv[0] = ph0; ka[0] = 0.0f;
    p0[1] = ph1; pwv[1] = ph1; ka[1] = 0.0f;
  }

  const float dtf = 0.03125f, half = 0.015625f;
  const float sixth = (float)(0.03125/6.0);

  for (int e = 0; e < 64; ++e) {
    float csv[2], snv[2];
    // ---- Phase A: all 64 lanes, 2 phases each; cache sin/cos for RK4 reuse
    {
      #pragma unroll
      for (int r = 0; r < 2; ++r) {
        snv[r] = __sinf(pwv[r]);
        csv[r] = __cosf(pwv[r]);
      }
      unsigned cp = __builtin_amdgcn_cvt_pk_fp8_f32(csv[0], csv[1], 0, false);
      unsigned sp = __builtin_amdgcn_cvt_pk_fp8_f32(snv[0], snv[1], 0, false);
      const int u = (w*4 + j4)*2 + (q >> 1);
      char* base = smem + A1_OFF + row2*2048 + ((q & 1) << 2) + rp*2;
      *(unsigned short*)(base + ((u ^ swz) << 3))        = (unsigned short)cp;
      *(unsigned short*)(base + 1024 + ((u ^ swz) << 3)) = (unsigned short)sp;
    }
    __syncthreads();

    // ---- GEMM1 fp8: m[p][row]; wave = (pt=w&7, kh=w>>3); independent cos/sin accs
    {
      const int pt = w & 7, kh = w >> 3;
      f32x4 accC = {0.f, 0.f, 0.f, 0.f}, accS = {0.f, 0.f, 0.f, 0.f};
      const char* t1b = T1g + (size_t)((pt*32 + kh*16)*64 + lane)*16;
      const char* a1b = smem + A1_OFF + row2*2048;
      #pragma unroll 8
      for (int i2 = 0; i2 < 16; ++i2) {
        const int ktc = kh*16 + i2;
        i64x2 af = *(const i64x2*)(t1b + (size_t)i2*1024);
        long bc = *(const long*)(a1b + (((ktc*4 + q) ^ swz) << 3));
        long bs = *(const long*)(a1b + 1024 + (((ktc*4 + q) ^ swz) << 3));
        accC = __builtin_amdgcn_mfma_f32_16x16x32_fp8_fp8(af[0], bc, accC, 0, 0, 0);
        accS = __builtin_amdgcn_mfma_f32_16x16x32_fp8_fp8(af[1], bs, accS, 0, 0, 0);
      }
      if (b16 < 2) {
        f32x4 acc = accC + accS;
        *(f32x4*)(smem + MBUF_OFF + kh*1056 + b16*528 + ((pt*16 + q*4) << 2)) = acc;
      }
    }
    __syncthreads();

    // ---- softmax (waves 0..1, wave = row): w fp8 prescaled x64; single store,
    // GEMM2 reads W row (b16&1) directly.
    if (w < 2) {
      const char* mb = smem + MBUF_OFF + w*528 + lane*8;
      f32x2 u0 = *(const f32x2*)(mb);
      f32x2 u1 = *(const f32x2*)(mb + 1056);
      float e0 = __expf((u0[0] + u1[0]) * 0.001953125f);  // BETA/N = 2/1024
      float e1 = __expf((u0[1] + u1[1]) * 0.001953125f);
      float s = e0 + e1;
      #pragma unroll
      for (int off = 1; off < 64; off <<= 1) s += __shfl_xor(s, off, 64);
      const float inv64 = 64.0f / s;
      unsigned pk = __builtin_amdgcn_cvt_pk_fp8_f32(e0*inv64, e1*inv64, 0, false);
      const int pp = lane*2, u = pp >> 3;
      *(unsigned short*)(smem + W_OFF + w*128 + ((u ^ w) << 3) + (pp & 7)) =
          (unsigned short)pk;
    }
    __syncthreads();

    // ---- GEMM2 fp8 + RK4: waves 0..8 read T2 from LDS (ds_read_b128), waves
    // 9..15 stream global.  4 ct accumulators; lane selects (j4, rp); 2-phase
    // RK4 with cached trig.
    {
      const float swt = tc.s[e], cwt = tc.c[e];
      const int st = e & 3;
      long wfr[4];
      #pragma unroll
      for (int pt2 = 0; pt2 < 4; ++pt2)
        wfr[pt2] = *(const long*)(smem + W_OFF + row2*128 + (((pt2*4 + q) ^ row2) << 3));
      f32x4 aC[4] = {{0,0,0,0},{0,0,0,0},{0,0,0,0},{0,0,0,0}};
      f32x4 aS[4] = {{0,0,0,0},{0,0,0,0},{0,0,0,0},{0,0,0,0}};
      if (w < 9) {
        const char* t2Lb = smem + T2L_OFF + (size_t)(w*16*64 + lane)*16;
        #pragma unroll
        for (int c = 0; c < 4; ++c)
          #pragma unroll
          for (int pt2 = 0; pt2 < 4; ++pt2) {
            i64x2 tf = *(const i64x2*)(t2Lb + (size_t)(c*4 + pt2)*1024);
            aC[c] = __builtin_amdgcn_mfma_f32_16x16x32_fp8_fp8(tf[0], wfr[pt2], aC[c], 0,0,0);
            aS[c] = __builtin_amdgcn_mfma_f32_16x16x32_fp8_fp8(tf[1], wfr[pt2], aS[c], 0,0,0);
          }
      } else {
        const char* t2b = T2g + (size_t)(w*16*64 + lane)*16;
        #pragma unroll
        for (int c = 0; c < 4; ++c)
          #pragma unroll
          for (int pt2 = 0; pt2 < 4; ++pt2) {
            i64x2 tf = *(const i64x2*)(t2b + (size_t)(c*4 + pt2)*1024);
            aC[c] = __builtin_amdgcn_mfma_f32_16x16x32_fp8_fp8(tf[0], wfr[pt2], aC[c], 0,0,0);
            aS[c] = __builtin_amdgcn_mfma_f32_16x16x32_fp8_fp8(tf[1], wfr[pt2], aS[c], 0,0,0);
          }
      }
      f32x4 c4 = (j4==0) ? aC[0] : (j4==1) ? aC[1] : (j4==2) ? aC[2] : aC[3];
      f32x4 s4 = (j4==0) ? aS[0] : (j4==1) ? aS[1] : (j4==2) ? aS[2] : aS[3];
      float vC[2], vS[2];
      vC[0] = rp ? c4[2] : c4[0];  vC[1] = rp ? c4[3] : c4[1];
      vS[0] = rp ? s4[2] : s4[0];  vS[1] = rp ? s4[3] : s4[1];
      #pragma unroll
      for (int r = 0; r < 2; ++r) {
        float s_ = snv[r];
        float c_ = csv[r];
        float kv = (s_*vC[r] - c_*vS[r]) * 0.015625f   // /64 rescale
                 + 0.08f*(swt*c_ - cwt*s_);            // A*sin(wt - phi)
        if (st == 0)      { ka[r]  = kv;           pwv[r] = p0[r] + kv*half; }
        else if (st == 1) { ka[r] += 2.0f*kv;      pwv[r] = p0[r] + kv*half; }
        else if (st == 2) { ka[r] += 2.0f*kv;      pwv[r] = p0[r] + kv*dtf;  }
        else { ka[r] += kv; p0[r] += ka[r]*sixth; pwv[r] = p0[r]; }
      }
    }
  }

  // ---- epilogue (bf16 MFMA): out = [cos phiT, sin phiT] @ W_out^T + b_out
  __syncthreads();
  {  // pack feats bf16 into A1 region (rows 0..1, 4-KB stride); all lanes, 2 each
    u16x2 cp, sp;
    #pragma unroll
    for (int r = 0; r < 2; ++r) {
      float ph = p0[r];
      cp[r] = f2bf(__cosf(ph)); sp[r] = f2bf(__sinf(ph));
    }
    const int cj = (w*4 + j4)*2 + (q >> 1);
    char* base = smem + A1_OFF + row2*4096 + ((q & 1) << 3) + rp*4;
    *(u16x2*)(base + ((cj ^ row2) << 4))        = cp;
    *(u16x2*)(base + ((cj ^ row2) << 4) + 2048) = sp;
  }
  __syncthreads();
  {  // D[cl][row] partial over this wave's 4 ktiles; A = W_out rows (cl<10, pad 0)
    f32x4 acc = {0.f, 0.f, 0.f, 0.f};
    #pragma unroll
    for (int i2 = 0; i2 < 4; ++i2) {
      const int kt = w*4 + i2;
      const int k = kt*32 + q*8;
      bf16x8 afr = {0,0,0,0,0,0,0,0};
      if (b16 < 10) {
        f32x4 v0 = *(const f32x4*)(W_out + b16*2048 + k);
        f32x4 v1 = *(const f32x4*)(W_out + b16*2048 + k + 4);
        #pragma unroll
        for (int i = 0; i < 8; ++i) afr[i] = (short)f2bf(i < 4 ? v0[i] : v1[i-4]);
      }
      const char* baddr = (b16 < 2)
          ? (smem + A1_OFF + b16*4096 + ((((kt*4 + q) ^ b16) & 255) << 4))
          : (smem + ZP_OFF);
      bf16x8 bfr = *(const bf16x8*)baddr;
      acc = __builtin_amdgcn_mfma_f32_16x16x32_bf16(afr, bfr, acc, 0, 0, 0);
    }
    *(f32x4*)(smem + RED_OFF + ((w*64 + lane) << 4)) = acc;
  }
  __syncthreads();
  if (tid < 64) {   // reduce 16 wave-partials; lane: row = tid&15, cl = (tid>>4)*4+r
    f32x4 s = {0.f, 0.f, 0.f, 0.f};
    #pragma unroll
    for (int w2 = 0; w2 < 16; ++w2)
      s += *(const f32x4*)(smem + RED_OFF + ((w2*64 + tid) << 4));
    const int b = tid & 15, q2 = tid >> 4;
    if (b < 2) {
      #pragma unroll
      for (int r = 0; r < 4; ++r) {
        const int cl = q2*4 + r;
        if (cl < 10)
          dout[(bk*2 + b)*10 + cl] = s[r] + b_out[cl];
      }
    }
  }
}

extern "C" void kernel_launch(void* const* d_in, const int* in_sizes, int n_in,
                              void* d_out, int out_size, void* d_ws, size_t ws_size,
                              hipStream_t stream) {
  (void)in_sizes; (void)n_in; (void)ws_size; (void)out_size;
  const float* x     = (const float*)d_in[0];
  const float* W_enc = (const float*)d_in[1];
  const float* b_enc = (const float*)d_in[2];
  const float* xi    = (const float*)d_in[3];
  const float* W_out = (const float*)d_in[4];
  const float* b_out = (const float*)d_in[5];
  float* out = (float*)d_out;
  char* wsb = (char*)d_ws;   // 512 KiB fp8 tables; T1 + T2(ct>=36) rewritten per launch

  TCons tc;
  const double OME = 2.0 * 3.14159265358979323846 * 200.0;
  const double dtd = 0.03125;
  const double co[4] = {0.0, 0.5, 0.5, 1.0};
  for (int e = 0; e < 64; ++e) {
    double t = ((double)(e >> 2) + co[e & 3]) * dtd;
    tc.s[e] = (float)sin(OME * t);
    tc.c[e] = (float)cos(OME * t);
  }

  phasenn_kernel<<<dim3(128), dim3(1024), 0, stream>>>(
      x, W_enc, b_enc, xi, W_out, b_out, out, wsb, tc);
}